// Round 1
// baseline (3235.604 us; speedup 1.0000x reference)
//
#include <hip/hip_runtime.h>
#include <cmath>

// GemmaAttention fp32 baseline:
//   gemm128 (Q/K/V proj) -> rope -> flash attention (fp32, shuffle softmax) -> gemm128 (O proj)
// H=8, KVH=1, HD=256, d_k=256 (scale 1/16). All fp32 for accuracy headroom.

#define H_NUM 8
#define HDIM 256

// ---------------------------------------------------------------------------
// Tiled fp32 GEMM: C = A(MxK) @ W(KxN), A,W row-major.
// 128x128 tile, TK=16, 256 threads, 8x8 per thread.
// mode 0: C[m*N + n]
// mode 1: q-layout: m=(b,s), n=(h,hd) -> C[((b*8+h)*S + s)*256 + hd]
// ---------------------------------------------------------------------------
__launch_bounds__(256, 2)
__global__ void ga_gemm128(const float* __restrict__ A, const float* __restrict__ W,
                           float* __restrict__ C, int M, int N, int K, int mode, int S) {
  __shared__ float As[16][132];  // [kk][m], +4 pad keeps f4 rows 16B-aligned, stores 2-way
  __shared__ float Bs[16][132];  // [kk][n]

  const int tid = threadIdx.x;
  const int tx = tid & 15;        // 16 col-threads
  const int ty = tid >> 4;        // 16 row-threads
  const int m0 = blockIdx.y * 128;
  const int n0 = blockIdx.x * 128;

  float acc[8][8];
#pragma unroll
  for (int i = 0; i < 8; ++i)
#pragma unroll
    for (int j = 0; j < 8; ++j) acc[i][j] = 0.f;

  for (int k0 = 0; k0 < K; k0 += 16) {
    // A tile: 128 rows x 16 k  (2048 elems, 8 per thread)
#pragma unroll
    for (int r = 0; r < 8; ++r) {
      const int idx = tid + r * 256;
      const int mm = idx >> 4, kk = idx & 15;
      As[kk][mm] = A[(size_t)(m0 + mm) * K + (k0 + kk)];
    }
    // B tile: 16 k x 128 cols
#pragma unroll
    for (int r = 0; r < 8; ++r) {
      const int idx = tid + r * 256;
      const int kk = idx >> 7, nn = idx & 127;
      Bs[kk][nn] = W[(size_t)(k0 + kk) * N + (n0 + nn)];
    }
    __syncthreads();

#pragma unroll
    for (int kk = 0; kk < 16; ++kk) {
      const float4 a0 = *(const float4*)&As[kk][ty * 8];
      const float4 a1 = *(const float4*)&As[kk][ty * 8 + 4];
      // split B fragment: cols tx*4..+3 and 64+tx*4..+3 (keeps LDS reads 2-way = free)
      const float4 b0 = *(const float4*)&Bs[kk][tx * 4];
      const float4 b1 = *(const float4*)&Bs[kk][64 + tx * 4];
      const float av[8] = {a0.x, a0.y, a0.z, a0.w, a1.x, a1.y, a1.z, a1.w};
      const float bv[8] = {b0.x, b0.y, b0.z, b0.w, b1.x, b1.y, b1.z, b1.w};
#pragma unroll
      for (int i = 0; i < 8; ++i)
#pragma unroll
        for (int j = 0; j < 8; ++j) acc[i][j] += av[i] * bv[j];
    }
    __syncthreads();
  }

#pragma unroll
  for (int i = 0; i < 8; ++i) {
    const int m = m0 + ty * 8 + i;
    const float4 st0 = make_float4(acc[i][0], acc[i][1], acc[i][2], acc[i][3]);
    const float4 st1 = make_float4(acc[i][4], acc[i][5], acc[i][6], acc[i][7]);
    if (mode == 0) {
      *(float4*)&C[(size_t)m * N + (n0 + tx * 4)] = st0;
      *(float4*)&C[(size_t)m * N + (n0 + 64 + tx * 4)] = st1;
    } else {
      const int b_ = m / S, s_ = m % S;
      const int n1 = n0 + tx * 4;
      const int n2 = n0 + 64 + tx * 4;
      *(float4*)&C[(((size_t)b_ * H_NUM + (n1 >> 8)) * S + s_) * HDIM + (n1 & 255)] = st0;
      *(float4*)&C[(((size_t)b_ * H_NUM + (n2 >> 8)) * S + s_) * HDIM + (n2 & 255)] = st1;
    }
  }
}

// ---------------------------------------------------------------------------
// RoPE. inv_freq = 10000^(-j/128) = exp(-j * ln(10000)/128). Pair (j, j+128).
// ---------------------------------------------------------------------------
#define ROPE_C (-0.07195578415606394f)  // -ln(10000)/128

__global__ void ga_rope_q(float* __restrict__ q, const int* __restrict__ pos, int S) {
  const int idx = blockIdx.x * 256 + threadIdx.x;  // B*H*S*128 threads
  const int j = idx & 127;
  const int t = idx >> 7;
  const int s = t % S;
  const int bh = t / S;          // b*H + h
  const int b = bh >> 3;
  const float p = (float)pos[b * S + s];
  const float inv = expf((float)j * ROPE_C);
  float sn, cs;
  sincosf(p * inv, &sn, &cs);
  float* base = q + ((size_t)bh * S + s) * HDIM;
  const float x1 = base[j], x2 = base[j + 128];
  base[j] = x1 * cs - x2 * sn;
  base[j + 128] = x2 * cs + x1 * sn;
}

__global__ void ga_rope_k(float* __restrict__ k, const int* __restrict__ pos, int S) {
  const int idx = blockIdx.x * 256 + threadIdx.x;  // B*S*128 threads
  const int j = idx & 127;
  const int t = idx >> 7;
  const int s = t % S;
  const int b = t / S;
  const float p = (float)pos[b * S + s];
  const float inv = expf((float)j * ROPE_C);
  float sn, cs;
  sincosf(p * inv, &sn, &cs);
  float* base = k + ((size_t)b * S + s) * HDIM;
  const float x1 = base[j], x2 = base[j + 128];
  base[j] = x1 * cs - x2 * sn;
  base[j + 128] = x2 * cs + x1 * sn;
}

// ---------------------------------------------------------------------------
// Flash attention, fp32. BQ=BK=32. Exactly 64KB LDS:
//   Qs 32x256 (32KB, xor-swizzled) + KVs 32x256 (32KB, holds K then V per block).
// Softmax stats + P broadcast are done with wave shuffles (no Ps buffer).
// Thread (tx=tid&15, ty=tid>>4): score rows {ty, ty+16}, cols {tx, tx+16};
// output rows {ty, ty+16}, cols tx*4 + j + 64*g.
// ---------------------------------------------------------------------------
__device__ __forceinline__ int swz(int r, int c) {
  // xor-swizzle at float4 granularity: conflict-free column reads
  return (r << 8) + ((((c >> 2) ^ (r & 7)) << 2) | (c & 3));
}

__launch_bounds__(256, 2)
__global__ void ga_flash(const float* __restrict__ q, const float* __restrict__ kg,
                         const float* __restrict__ vg, const float* __restrict__ msk,
                         float* __restrict__ o, int S) {
  __shared__ float Qs[32 * 256];
  __shared__ float KVs[32 * 256];

  const int tid = threadIdx.x;
  const int tx = tid & 15;
  const int ty = tid >> 4;
  const int nqb = S / 32;
  const int qbi = blockIdx.x % nqb;
  const int h = (blockIdx.x / nqb) % H_NUM;
  const int b = blockIdx.x / (nqb * H_NUM);
  const int q0 = qbi * 32;

  // stage Q tile (contiguous 32x256 block of (b,h,s,hd) layout)
  const float* qbase = q + (((size_t)b * H_NUM + h) * S + q0) * HDIM;
#pragma unroll
  for (int r = 0; r < 8; ++r) {
    const int i4 = tid + r * 256;            // float4 index, 2048 total
    const int row = i4 >> 6, c = (i4 & 63) << 2;
    *(float4*)&Qs[swz(row, c)] = *(const float4*)&qbase[(size_t)i4 << 2];
  }

  float accA[4][4], accB[4][4];
#pragma unroll
  for (int g = 0; g < 4; ++g)
#pragma unroll
    for (int j = 0; j < 4; ++j) { accA[g][j] = 0.f; accB[g][j] = 0.f; }

  float m0 = -INFINITY, m1 = -INFINITY, l0 = 0.f, l1 = 0.f;

  const float* kbase = kg + (size_t)b * S * HDIM;
  const float* vbase = vg + (size_t)b * S * HDIM;
  const float* mrow0 = msk + (size_t)b * S * S + (size_t)(q0 + ty) * S;
  const float* mrow1 = msk + (size_t)b * S * S + (size_t)(q0 + ty + 16) * S;

  for (int k0 = 0; k0 < S; k0 += 32) {
    __syncthreads();  // previous PV (and initial Q staging) done with KVs
    // stage K tile
#pragma unroll
    for (int r = 0; r < 8; ++r) {
      const int i4 = tid + r * 256;
      const int row = i4 >> 6, c = (i4 & 63) << 2;
      *(float4*)&KVs[swz(row, c)] = *(const float4*)&kbase[((size_t)k0 << 8) + ((size_t)i4 << 2)];
    }
    __syncthreads();

    // scores: 2x2 per thread over d=256
    float s00 = 0.f, s01 = 0.f, s10 = 0.f, s11 = 0.f;
#pragma unroll 4
    for (int i = 0; i < HDIM; i += 4) {
      const float4 qa = *(const float4*)&Qs[swz(ty, i)];
      const float4 qc = *(const float4*)&Qs[swz(ty + 16, i)];
      const float4 ka = *(const float4*)&KVs[swz(tx, i)];
      const float4 kb = *(const float4*)&KVs[swz(tx + 16, i)];
      s00 += qa.x * ka.x + qa.y * ka.y + qa.z * ka.z + qa.w * ka.w;
      s01 += qa.x * kb.x + qa.y * kb.y + qa.z * kb.z + qa.w * kb.w;
      s10 += qc.x * ka.x + qc.y * ka.y + qc.z * ka.z + qc.w * ka.w;
      s11 += qc.x * kb.x + qc.y * kb.y + qc.z * kb.z + qc.w * kb.w;
    }
    const float sc = 0.0625f;  // 1/sqrt(256)
    s00 = s00 * sc + mrow0[k0 + tx];
    s01 = s01 * sc + mrow0[k0 + tx + 16];
    s10 = s10 * sc + mrow1[k0 + tx];
    s11 = s11 * sc + mrow1[k0 + tx + 16];
    __syncthreads();  // scores done reading KVs

    // stage V tile into KVs (overlaps the shuffle-stats below)
#pragma unroll
    for (int r = 0; r < 8; ++r) {
      const int i4 = tid + r * 256;
      const int row = i4 >> 6, c = (i4 & 63) << 2;
      *(float4*)&KVs[swz(row, c)] = *(const float4*)&vbase[((size_t)k0 << 8) + ((size_t)i4 << 2)];
    }

    // online softmax stats per row, via xor-shuffles over the 16-lane tx group
    float mloc0 = fmaxf(s00, s01);
    float mloc1 = fmaxf(s10, s11);
#pragma unroll
    for (int d = 1; d < 16; d <<= 1) {
      mloc0 = fmaxf(mloc0, __shfl_xor(mloc0, d, 64));
      mloc1 = fmaxf(mloc1, __shfl_xor(mloc1, d, 64));
    }
    const float mn0 = fmaxf(m0, mloc0);
    const float mn1 = fmaxf(m1, mloc1);
    const float al0 = __expf(m0 - mn0);
    const float al1 = __expf(m1 - mn1);
    const float p00 = __expf(s00 - mn0);
    const float p01 = __expf(s01 - mn0);
    const float p10 = __expf(s10 - mn1);
    const float p11 = __expf(s11 - mn1);
    float rs0 = p00 + p01;
    float rs1 = p10 + p11;
#pragma unroll
    for (int d = 1; d < 16; d <<= 1) {
      rs0 += __shfl_xor(rs0, d, 64);
      rs1 += __shfl_xor(rs1, d, 64);
    }
    l0 = l0 * al0 + rs0;
    l1 = l1 * al1 + rs1;
    m0 = mn0;
    m1 = mn1;

    __syncthreads();  // V staged

    // rescale accumulators, then accumulate P@V
#pragma unroll
    for (int g = 0; g < 4; ++g)
#pragma unroll
      for (int j = 0; j < 4; ++j) { accA[g][j] *= al0; accB[g][j] *= al1; }

#pragma unroll 8
    for (int kk = 0; kk < 32; ++kk) {
      const int src = (tid & 48) | (kk & 15);  // lane holding P(row, kk): same ty, tx = kk%16
      const float pa = __shfl((kk < 16) ? p00 : p01, src, 64);
      const float pb = __shfl((kk < 16) ? p10 : p11, src, 64);
#pragma unroll
      for (int g = 0; g < 4; ++g) {
        const float4 vv = *(const float4*)&KVs[swz(kk, (tx << 2) + (g << 6))];
        accA[g][0] += pa * vv.x; accA[g][1] += pa * vv.y; accA[g][2] += pa * vv.z; accA[g][3] += pa * vv.w;
        accB[g][0] += pb * vv.x; accB[g][1] += pb * vv.y; accB[g][2] += pb * vv.z; accB[g][3] += pb * vv.w;
      }
    }
  }

  // epilogue: normalize and store to (b, s, h*hd)
  const float li0 = 1.f / l0;
  const float li1 = 1.f / l1;
  float* ob0 = o + (size_t)(b * S + q0 + ty) * (H_NUM * HDIM) + h * HDIM;
  float* ob1 = o + (size_t)(b * S + q0 + ty + 16) * (H_NUM * HDIM) + h * HDIM;
#pragma unroll
  for (int g = 0; g < 4; ++g) {
    const float4 st0 = make_float4(accA[g][0] * li0, accA[g][1] * li0, accA[g][2] * li0, accA[g][3] * li0);
    const float4 st1 = make_float4(accB[g][0] * li1, accB[g][1] * li1, accB[g][2] * li1, accB[g][3] * li1);
    *(float4*)&ob0[(tx << 2) + (g << 6)] = st0;
    *(float4*)&ob1[(tx << 2) + (g << 6)] = st1;
  }
}

// ---------------------------------------------------------------------------
extern "C" void kernel_launch(void* const* d_in, const int* in_sizes, int n_in,
                              void* d_out, int out_size, void* d_ws, size_t ws_size,
                              hipStream_t stream) {
  const float* hs   = (const float*)d_in[0];
  const float* mask = (const float*)d_in[1];
  const int*   pos  = (const int*)d_in[2];
  const float* Wq   = (const float*)d_in[3];
  const float* Wk   = (const float*)d_in[4];
  const float* Wv   = (const float*)d_in[5];
  const float* Wo   = (const float*)d_in[6];
  float* out = (float*)d_out;

  const int S = 2048, D = 2048;
  const int B = in_sizes[2] / S;   // position_ids is (B,S)
  const int M = B * S;

  // q lives in d_out (same size as the final output; overwritten by O-proj at the end)
  float* qb = out;
  float* ws = (float*)d_ws;
  float* kb = ws;                              // B*S*256
  float* vb = kb + (size_t)B * S * HDIM;       // B*S*256
  float* ao = vb + (size_t)B * S * HDIM;       // B*S*2048 (attn out, (b,s,h*hd))

  const dim3 blk(256);
  // projections
  ga_gemm128<<<dim3(D / 128, M / 128), blk, 0, stream>>>(hs, Wq, qb, M, D, D, 1, S);
  ga_gemm128<<<dim3(HDIM / 128, M / 128), blk, 0, stream>>>(hs, Wk, kb, M, HDIM, D, 0, S);
  ga_gemm128<<<dim3(HDIM / 128, M / 128), blk, 0, stream>>>(hs, Wv, vb, M, HDIM, D, 0, S);
  // rope
  ga_rope_q<<<(B * H_NUM * S * 128) / 256, blk, 0, stream>>>(qb, pos, S);
  ga_rope_k<<<(B * S * 128) / 256, blk, 0, stream>>>(kb, pos, S);
  // attention
  ga_flash<<<B * H_NUM * (S / 32), blk, 0, stream>>>(qb, kb, vb, mask, ao, S);
  // output projection
  ga_gemm128<<<dim3(D / 128, M / 128), blk, 0, stream>>>(ao, Wo, out, M, D, D, 0, S);
}

// Round 3
// 519.080 us; speedup vs baseline: 6.2333x; 6.2333x over previous
//
#include <hip/hip_runtime.h>
#include <cmath>

// GemmaAttention bf16-MFMA pipeline:
//   cvt(hs) + transpose-cvt(W*) -> MFMA gemm (Q/KV proj) -> rope(bf16) ->
//   MFMA flash attention (fp32 softmax) -> MFMA gemm (O proj, fp32 out)
// All MFMA = v_mfma_f32_16x16x32_bf16. fp32 accumulate everywhere.
// R3 fix: __syncthreads() between P LDS store and P LDS load in flash
// (same-wave DS ordering was the only unprotected dependency; post-timing
// divergence in R2 was stable-wrong across warm replays, pointing here).

typedef __bf16 bf16;
typedef __attribute__((ext_vector_type(8))) __bf16 bf16x8;
typedef __attribute__((ext_vector_type(4))) __bf16 bf16x4;
typedef __attribute__((ext_vector_type(4))) float f32x4;

#define S_LEN 2048
#define D_MODEL 2048
#define H_NUM 8
#define HDIM 256
#define LDK 40   // GEMM LDS k-pitch (32+8 bf16) — 80B rows, 16B aligned
#define QP 264   // flash Q/K LDS pitch (256+8)
#define VP 40    // flash V/P LDS pitch (32+8)

__global__ void cvt_bf16(const float* __restrict__ src, bf16* __restrict__ dst) {
  const int i = (blockIdx.x * 256 + threadIdx.x) * 4;
  const float4 v = *(const float4*)(src + i);
  bf16x4 o;
  o[0] = (bf16)v.x; o[1] = (bf16)v.y; o[2] = (bf16)v.z; o[3] = (bf16)v.w;
  *(bf16x4*)(dst + i) = o;
}

__global__ void tpose_cvt(const float* __restrict__ W, bf16* __restrict__ Wt,
                          int Ncols, int no0) {
  __shared__ float t[32][33];
  const int tx = threadIdx.x, ty = threadIdx.y;  // (32,8)
  const int n0 = blockIdx.x * 32, k0 = blockIdx.y * 32;
#pragma unroll
  for (int i = 0; i < 4; ++i)
    t[ty + 8 * i][tx] = W[(size_t)(k0 + ty + 8 * i) * Ncols + (n0 + tx)];
  __syncthreads();
#pragma unroll
  for (int i = 0; i < 4; ++i)
    Wt[(size_t)(no0 + n0 + ty + 8 * i) * D_MODEL + (k0 + tx)] = (bf16)t[tx][ty + 8 * i];
}

// C = A(MxK) @ Wt(NxK)^T, K=2048. 128x128 tile, BK=32, 4 waves x 64x64.
// mode 1: q (b,h,s,hd) bf16; mode 2: kv split (k:(b,s,hd), v:(b,hd,s)) bf16;
// mode 3: fp32 row-major.
__global__ __launch_bounds__(256)
void gemm_bf16(const bf16* __restrict__ A, const bf16* __restrict__ Wt,
               void* __restrict__ Cout, int M, int N, int mode) {
  __shared__ bf16 As[128 * LDK];
  __shared__ bf16 Bs[128 * LDK];
  const int tid = threadIdx.x;
  const int lane = tid & 63;
  const int wave = tid >> 6;
  const int c16 = lane & 15;
  const int quad = lane >> 4;
  const int wr = wave >> 1, wc = wave & 1;
  const int m0 = blockIdx.y * 128, n0 = blockIdx.x * 128;
  const int K = D_MODEL;

  f32x4 acc[4][4];
#pragma unroll
  for (int i = 0; i < 4; ++i)
#pragma unroll
    for (int j = 0; j < 4; ++j)
#pragma unroll
      for (int r = 0; r < 4; ++r) acc[i][j][r] = 0.f;

  const int srow = tid >> 2, sq4 = tid & 3;
  for (int k0 = 0; k0 < K; k0 += 32) {
#pragma unroll
    for (int i = 0; i < 2; ++i) {
      const int row = srow + i * 64;
      *(bf16x8*)&As[row * LDK + sq4 * 8] =
          *(const bf16x8*)&A[(size_t)(m0 + row) * K + k0 + sq4 * 8];
      *(bf16x8*)&Bs[row * LDK + sq4 * 8] =
          *(const bf16x8*)&Wt[(size_t)(n0 + row) * K + k0 + sq4 * 8];
    }
    __syncthreads();
    bf16x8 af[4], bfr[4];
#pragma unroll
    for (int i = 0; i < 4; ++i)
      af[i] = *(const bf16x8*)&As[(wr * 64 + i * 16 + c16) * LDK + quad * 8];
#pragma unroll
    for (int j = 0; j < 4; ++j)
      bfr[j] = *(const bf16x8*)&Bs[(wc * 64 + j * 16 + c16) * LDK + quad * 8];
#pragma unroll
    for (int i = 0; i < 4; ++i)
#pragma unroll
      for (int j = 0; j < 4; ++j)
        acc[i][j] = __builtin_amdgcn_mfma_f32_16x16x32_bf16(af[i], bfr[j], acc[i][j], 0, 0, 0);
    __syncthreads();
  }

#pragma unroll
  for (int i = 0; i < 4; ++i)
#pragma unroll
    for (int j = 0; j < 4; ++j) {
      const int n = n0 + wc * 64 + j * 16 + c16;
#pragma unroll
      for (int r = 0; r < 4; ++r) {
        const int m = m0 + wr * 64 + i * 16 + quad * 4 + r;
        const float val = acc[i][j][r];
        if (mode == 1) {
          const int b = m >> 11, s = m & 2047;
          const int h = n >> 8, hd = n & 255;
          ((bf16*)Cout)[((((size_t)b * H_NUM + h) * S_LEN + s) << 8) + hd] = (bf16)val;
        } else if (mode == 2) {
          const int b = m >> 11, s = m & 2047;
          if (n < 256)
            ((bf16*)Cout)[((size_t)m << 8) + n] = (bf16)val;
          else
            ((bf16*)Cout)[((size_t)M << 8) + ((size_t)((b << 8) + (n - 256)) * S_LEN) + s] = (bf16)val;
        } else {
          ((float*)Cout)[(size_t)m * N + n] = val;
        }
      }
    }
}

#define ROPE_C (-0.07195578415606394f)

__global__ void rope_q_bf16(bf16* __restrict__ q, const int* __restrict__ pos) {
  const int idx = blockIdx.x * 256 + threadIdx.x;
  const int j = idx & 127;
  const int t = idx >> 7;
  const int s = t & 2047;
  const int bh = t >> 11;
  const int b = bh >> 3;
  const float p = (float)pos[(b << 11) + s];
  float sn, cs;
  sincosf(p * expf((float)j * ROPE_C), &sn, &cs);
  bf16* base = q + (((size_t)bh << 11) + s) * HDIM;
  const float x1 = (float)base[j], x2 = (float)base[j + 128];
  base[j] = (bf16)(x1 * cs - x2 * sn);
  base[j + 128] = (bf16)(x2 * cs + x1 * sn);
}

__global__ void rope_k_bf16(bf16* __restrict__ k, const int* __restrict__ pos) {
  const int idx = blockIdx.x * 256 + threadIdx.x;
  const int j = idx & 127;
  const int t = idx >> 7;
  const int s = t & 2047;
  const int b = t >> 11;
  const float p = (float)pos[(b << 11) + s];
  float sn, cs;
  sincosf(p * expf((float)j * ROPE_C), &sn, &cs);
  bf16* base = k + (size_t)t * HDIM;
  const float x1 = (float)base[j], x2 = (float)base[j + 128];
  base[j] = (bf16)(x1 * cs - x2 * sn);
  base[j + 128] = (bf16)(x2 * cs + x1 * sn);
}

// Flash attention: BQ=64 (16 q-rows/wave), BK=32, d=256.
// q:(b,h,s,hd) k:(b,s,hd) v:(b,hd,s). LDS 74.5KB -> 2 blocks/CU.
__global__ __launch_bounds__(256, 2)
void flash_bf16(const bf16* __restrict__ qg, const bf16* __restrict__ kg,
                const bf16* __restrict__ vg, const float* __restrict__ msk,
                bf16* __restrict__ ao) {
  __shared__ bf16 Qs[64 * QP];
  __shared__ bf16 Ks[32 * QP];
  __shared__ bf16 Vs[256 * VP];
  __shared__ bf16 Ps[4 * 16 * VP];

  const int tid = threadIdx.x;
  const int lane = tid & 63;
  const int w = tid >> 6;
  const int c16 = lane & 15;
  const int quad = lane >> 4;

  const int qbi = blockIdx.x & 31;
  const int h = (blockIdx.x >> 5) & 7;
  const int b = blockIdx.x >> 8;
  const int q0 = qbi * 64;

  const bf16* qbase = qg + ((((size_t)b * H_NUM + h) * S_LEN + q0) << 8);
  const bf16* kbase = kg + ((size_t)b * S_LEN << 8);
  const bf16* vbase = vg + ((size_t)b << 8) * S_LEN;

#pragma unroll
  for (int i = 0; i < 8; ++i) {
    const int idx = tid + i * 256;
    const int row = idx >> 5, q16 = idx & 31;
    *(bf16x8*)&Qs[row * QP + q16 * 8] = *(const bf16x8*)&qbase[(row << 8) + q16 * 8];
  }

  f32x4 oacc[16];
#pragma unroll
  for (int t = 0; t < 16; ++t)
#pragma unroll
    for (int r = 0; r < 4; ++r) oacc[t][r] = 0.f;
  float mrow[4] = {-1e30f, -1e30f, -1e30f, -1e30f};
  float lrow[4] = {0.f, 0.f, 0.f, 0.f};

  for (int k0 = 0; k0 < S_LEN; k0 += 32) {
    __syncthreads();
#pragma unroll
    for (int i = 0; i < 4; ++i) {
      const int idx = tid + i * 256;
      const int krow = idx >> 5, kq = idx & 31;
      *(bf16x8*)&Ks[krow * QP + kq * 8] =
          *(const bf16x8*)&kbase[((size_t)(k0 + krow) << 8) + kq * 8];
      const int vrow = idx >> 2, vq = idx & 3;
      *(bf16x8*)&Vs[vrow * VP + vq * 8] =
          *(const bf16x8*)&vbase[(size_t)vrow * S_LEN + k0 + vq * 8];
    }
    __syncthreads();

    f32x4 sc[2];
#pragma unroll
    for (int ct = 0; ct < 2; ++ct)
#pragma unroll
      for (int r = 0; r < 4; ++r) sc[ct][r] = 0.f;
#pragma unroll
    for (int kd = 0; kd < 8; ++kd) {
      const bf16x8 aq = *(const bf16x8*)&Qs[(w * 16 + c16) * QP + kd * 32 + quad * 8];
      const bf16x8 b0 = *(const bf16x8*)&Ks[c16 * QP + kd * 32 + quad * 8];
      const bf16x8 b1 = *(const bf16x8*)&Ks[(16 + c16) * QP + kd * 32 + quad * 8];
      sc[0] = __builtin_amdgcn_mfma_f32_16x16x32_bf16(aq, b0, sc[0], 0, 0, 0);
      sc[1] = __builtin_amdgcn_mfma_f32_16x16x32_bf16(aq, b1, sc[1], 0, 0, 0);
    }

    const float* mbase = msk + (size_t)b * S_LEN * S_LEN +
                         (size_t)(q0 + w * 16 + quad * 4) * S_LEN + k0;
    float sv[2][4];
#pragma unroll
    for (int ct = 0; ct < 2; ++ct)
#pragma unroll
      for (int r = 0; r < 4; ++r)
        sv[ct][r] = sc[ct][r] * 0.0625f + mbase[(size_t)r * S_LEN + ct * 16 + c16];

    float mloc[4], al[4], pv[2][4], rs[4];
#pragma unroll
    for (int r = 0; r < 4; ++r) mloc[r] = fmaxf(sv[0][r], sv[1][r]);
#pragma unroll
    for (int d = 1; d < 16; d <<= 1)
#pragma unroll
      for (int r = 0; r < 4; ++r) mloc[r] = fmaxf(mloc[r], __shfl_xor(mloc[r], d, 64));
#pragma unroll
    for (int r = 0; r < 4; ++r) {
      const float mn = fmaxf(mrow[r], mloc[r]);
      al[r] = __expf(mrow[r] - mn);
      pv[0][r] = __expf(sv[0][r] - mn);
      pv[1][r] = __expf(sv[1][r] - mn);
      rs[r] = pv[0][r] + pv[1][r];
      mrow[r] = mn;
    }
#pragma unroll
    for (int d = 1; d < 16; d <<= 1)
#pragma unroll
      for (int r = 0; r < 4; ++r) rs[r] += __shfl_xor(rs[r], d, 64);
#pragma unroll
    for (int r = 0; r < 4; ++r) lrow[r] = lrow[r] * al[r] + rs[r];

    bf16* pw = &Ps[(w * 16) * VP];
#pragma unroll
    for (int ct = 0; ct < 2; ++ct)
#pragma unroll
      for (int r = 0; r < 4; ++r)
        pw[(quad * 4 + r) * VP + ct * 16 + c16] = (bf16)pv[ct][r];

    // R3 FIX: barrier-separate the P store (C-layout) from the P load
    // (A-layout). The write/read pair is per-wave, but relying on same-wave
    // DS-pipe ordering was the only unprotected memory dependency in the
    // pipeline and matches R2's stable post-timing divergence.
    __syncthreads();

#pragma unroll
    for (int t = 0; t < 16; ++t)
#pragma unroll
      for (int r = 0; r < 4; ++r) oacc[t][r] *= al[r];

    const bf16x8 pa = *(const bf16x8*)&Ps[(w * 16 + c16) * VP + quad * 8];
#pragma unroll
    for (int t = 0; t < 16; ++t) {
      const bf16x8 vb_ = *(const bf16x8*)&Vs[(t * 16 + c16) * VP + quad * 8];
      oacc[t] = __builtin_amdgcn_mfma_f32_16x16x32_bf16(pa, vb_, oacc[t], 0, 0, 0);
    }
  }

  float li[4];
#pragma unroll
  for (int r = 0; r < 4; ++r) li[r] = 1.f / lrow[r];
  bf16* obase = ao + (size_t)(b * S_LEN + q0 + w * 16 + quad * 4) * D_MODEL + (h << 8);
#pragma unroll
  for (int t = 0; t < 16; ++t)
#pragma unroll
    for (int r = 0; r < 4; ++r)
      obase[(size_t)r * D_MODEL + t * 16 + c16] = (bf16)(oacc[t][r] * li[r]);
}

extern "C" void kernel_launch(void* const* d_in, const int* in_sizes, int n_in,
                              void* d_out, int out_size, void* d_ws, size_t ws_size,
                              hipStream_t stream) {
  const float* hs   = (const float*)d_in[0];
  const float* mask = (const float*)d_in[1];
  const int*   pos  = (const int*)d_in[2];
  const float* Wq   = (const float*)d_in[3];
  const float* Wk   = (const float*)d_in[4];
  const float* Wv   = (const float*)d_in[5];
  const float* Wo   = (const float*)d_in[6];
  float* out = (float*)d_out;

  const int B = in_sizes[2] / S_LEN;
  const int M = B * S_LEN;

  // ws: [hsb|aob][Wkvt][Wot][kb][vb] = 31.5MB (R1 proved >=42MB available)
  char* wsc = (char*)d_ws;
  bf16* hsb = (bf16*)wsc;
  bf16* aob = hsb;  // flash output aliases hsb (dead by then)
  size_t off = (size_t)M * D_MODEL * 2;
  bf16* Wkvt = (bf16*)(wsc + off); off += (size_t)512 * D_MODEL * 2;
  bf16* Wot  = (bf16*)(wsc + off); off += (size_t)D_MODEL * D_MODEL * 2;
  bf16* kb   = (bf16*)(wsc + off);
  bf16* vb   = kb + (size_t)M * HDIM;

  // d_out as scratch: [qb 16.8M][Wqt 8.4M]; fully overwritten by O-proj
  bf16* qb  = (bf16*)d_out;
  bf16* Wqt = (bf16*)((char*)d_out + (size_t)M * D_MODEL * 2);

  const dim3 blk(256);
  const dim3 tb(32, 8);
  cvt_bf16<<<(M * D_MODEL) / 1024, blk, 0, stream>>>(hs, hsb);
  tpose_cvt<<<dim3(D_MODEL / 32, D_MODEL / 32), tb, 0, stream>>>(Wq, Wqt, D_MODEL, 0);
  tpose_cvt<<<dim3(HDIM / 32, D_MODEL / 32), tb, 0, stream>>>(Wk, Wkvt, HDIM, 0);
  tpose_cvt<<<dim3(HDIM / 32, D_MODEL / 32), tb, 0, stream>>>(Wv, Wkvt, HDIM, 256);
  tpose_cvt<<<dim3(D_MODEL / 32, D_MODEL / 32), tb, 0, stream>>>(Wo, Wot, D_MODEL, 0);

  gemm_bf16<<<dim3(D_MODEL / 128, M / 128), blk, 0, stream>>>(hsb, Wqt, qb, M, D_MODEL, 1);
  gemm_bf16<<<dim3(512 / 128, M / 128), blk, 0, stream>>>(hsb, Wkvt, kb, M, 512, 2);

  rope_q_bf16<<<(B * H_NUM * S_LEN * 128) / 256, blk, 0, stream>>>(qb, pos);
  rope_k_bf16<<<(B * S_LEN * 128) / 256, blk, 0, stream>>>(kb, pos);

  flash_bf16<<<B * H_NUM * (S_LEN / 64), blk, 0, stream>>>(qb, kb, vb, mask, aob);

  gemm_bf16<<<dim3(D_MODEL / 128, M / 128), blk, 0, stream>>>(aob, Wot, out, M, D_MODEL, 3);
}

// Round 4
// 453.003 us; speedup vs baseline: 7.1426x; 1.1459x over previous
//
#include <hip/hip_runtime.h>
#include <cmath>

// GemmaAttention bf16-MFMA pipeline, R4:
//   cvt(hs) + transpose-cvt(W*) -> fused QKV MFMA gemm (global_load_lds
//   staging, m97 recipe) -> rope -> flash v2 (BK=64, Q-in-regs, hoisted mask,
//   conditional rescale) -> O-proj MFMA gemm (fp32 out).
// All MFMA = v_mfma_f32_16x16x32_bf16, fp32 accumulate.

typedef __bf16 bf16;
typedef __attribute__((ext_vector_type(8))) __bf16 bf16x8;
typedef __attribute__((ext_vector_type(4))) __bf16 bf16x4;
typedef __attribute__((ext_vector_type(4))) float f32x4;

#define S_LEN 2048
#define D_MODEL 2048
#define H_NUM 8
#define HDIM 256
#define KP 264   // flash Ks pitch (256+8): 132 dw ≡ 4 mod 32 -> bank rotation
#define VP2 72   // flash Vs/Ps pitch (64+8): 36 dw ≡ 4 mod 32

// async global->LDS, 16B per lane. LDS dest is wave-uniform base + lane*16.
__device__ __forceinline__ void gl_lds16(const bf16* g, bf16* l) {
  __builtin_amdgcn_global_load_lds(
      (const __attribute__((address_space(1))) void*)g,
      (__attribute__((address_space(3))) void*)l, 16, 0, 0);
}

__global__ void cvt_bf16(const float* __restrict__ src, bf16* __restrict__ dst) {
  const int i = (blockIdx.x * 256 + threadIdx.x) * 4;
  const float4 v = *(const float4*)(src + i);
  bf16x4 o;
  o[0] = (bf16)v.x; o[1] = (bf16)v.y; o[2] = (bf16)v.z; o[3] = (bf16)v.w;
  *(bf16x4*)(dst + i) = o;
}

__global__ void tpose_cvt(const float* __restrict__ W, bf16* __restrict__ Wt,
                          int Ncols, int no0) {
  __shared__ float t[32][33];
  const int tx = threadIdx.x, ty = threadIdx.y;  // (32,8)
  const int n0 = blockIdx.x * 32, k0 = blockIdx.y * 32;
#pragma unroll
  for (int i = 0; i < 4; ++i)
    t[ty + 8 * i][tx] = W[(size_t)(k0 + ty + 8 * i) * Ncols + (n0 + tx)];
  __syncthreads();
#pragma unroll
  for (int i = 0; i < 4; ++i)
    Wt[(size_t)(no0 + n0 + ty + 8 * i) * D_MODEL + (k0 + tx)] = (bf16)t[tx][ty + 8 * i];
}

// C = A(Mx2048) @ Wt(Nx2048)^T. 128x128 tile, BK=32, 256 thr, 4 waves x 64x64.
// Staging via global_load_lds into UNPADDED lane-linear 128x32 tiles (m97).
// mode 1: fused QKV epilogue (n<2048 q-layout, <2304 k, else v-transposed);
// mode 3: fp32 row-major.
__global__ __launch_bounds__(256)
void gemm_bf16(const bf16* __restrict__ A, const bf16* __restrict__ Wt,
               bf16* __restrict__ Cq, bf16* __restrict__ Ck, bf16* __restrict__ Cv,
               float* __restrict__ Cf, int M, int N, int mode) {
  __shared__ bf16 As[128 * 32];
  __shared__ bf16 Bs[128 * 32];
  const int tid = threadIdx.x;
  const int lane = tid & 63;
  const int wbase = tid & 192;   // wave*64
  const int c16 = lane & 15;
  const int quad = lane >> 4;
  const int wave = tid >> 6;
  const int wr = wave >> 1, wc = wave & 1;
  const int m0 = blockIdx.y * 128, n0 = blockIdx.x * 128;

  f32x4 acc[4][4];
#pragma unroll
  for (int i = 0; i < 4; ++i)
#pragma unroll
    for (int j = 0; j < 4; ++j)
#pragma unroll
      for (int r = 0; r < 4; ++r) acc[i][j][r] = 0.f;

  for (int k0 = 0; k0 < D_MODEL; k0 += 32) {
#pragma unroll
    for (int j = 0; j < 2; ++j) {
      const int bslot = j * 256 + wbase;      // wave-uniform 16B slot base
      const int slot = bslot + lane;          // lane-linear: LDS = base + lane*16
      const int row = slot >> 2, ch = slot & 3;
      gl_lds16(&A[(size_t)(m0 + row) * D_MODEL + k0 + ch * 8], &As[bslot * 8]);
      gl_lds16(&Wt[(size_t)(n0 + row) * D_MODEL + k0 + ch * 8], &Bs[bslot * 8]);
    }
    __syncthreads();  // compiler drains vmcnt before s_barrier (m97)
    bf16x8 af[4], bfr[4];
#pragma unroll
    for (int i = 0; i < 4; ++i)
      af[i] = *(const bf16x8*)&As[(wr * 64 + i * 16 + c16) * 32 + quad * 8];
#pragma unroll
    for (int j = 0; j < 4; ++j)
      bfr[j] = *(const bf16x8*)&Bs[(wc * 64 + j * 16 + c16) * 32 + quad * 8];
#pragma unroll
    for (int i = 0; i < 4; ++i)
#pragma unroll
      for (int j = 0; j < 4; ++j)
        acc[i][j] = __builtin_amdgcn_mfma_f32_16x16x32_bf16(af[i], bfr[j], acc[i][j], 0, 0, 0);
    __syncthreads();
  }

  // epilogue. D layout: col=c16, row=quad*4+r.
#pragma unroll
  for (int i = 0; i < 4; ++i)
#pragma unroll
    for (int j = 0; j < 4; ++j) {
      const int n = n0 + wc * 64 + j * 16 + c16;
#pragma unroll
      for (int r = 0; r < 4; ++r) {
        const int m = m0 + wr * 64 + i * 16 + quad * 4 + r;
        const float val = acc[i][j][r];
        if (mode == 1) {
          const int b = m >> 11, s = m & 2047;
          if (n0 < 2048) {
            const int h = n >> 8, hd = n & 255;
            Cq[((((size_t)b * H_NUM + h) * S_LEN + s) << 8) + hd] = (bf16)val;
          } else if (n0 < 2304) {
            Ck[((size_t)m << 8) + (n - 2048)] = (bf16)val;
          } else {
            Cv[((size_t)((b << 8) + (n - 2304)) << 11) + s] = (bf16)val;
          }
        } else {
          Cf[(size_t)m * D_MODEL + n] = val;
        }
      }
    }
}

#define ROPE_C (-0.07195578415606394f)

__global__ void rope_q_bf16(bf16* __restrict__ q, const int* __restrict__ pos) {
  const int idx = blockIdx.x * 256 + threadIdx.x;
  const int j = idx & 127;
  const int t = idx >> 7;
  const int s = t & 2047;
  const int bh = t >> 11;
  const int b = bh >> 3;
  const float p = (float)pos[(b << 11) + s];
  float sn, cs;
  sincosf(p * expf((float)j * ROPE_C), &sn, &cs);
  bf16* base = q + (((size_t)bh << 11) + s) * HDIM;
  const float x1 = (float)base[j], x2 = (float)base[j + 128];
  base[j] = (bf16)(x1 * cs - x2 * sn);
  base[j + 128] = (bf16)(x2 * cs + x1 * sn);
}

__global__ void rope_k_bf16(bf16* __restrict__ k, const int* __restrict__ pos) {
  const int idx = blockIdx.x * 256 + threadIdx.x;
  const int j = idx & 127;
  const int t = idx >> 7;
  const int s = t & 2047;
  const int b = t >> 11;
  const float p = (float)pos[(b << 11) + s];
  float sn, cs;
  sincosf(p * expf((float)j * ROPE_C), &sn, &cs);
  bf16* base = k + (size_t)t * HDIM;
  const float x1 = (float)base[j], x2 = (float)base[j + 128];
  base[j] = (bf16)(x1 * cs - x2 * sn);
  base[j + 128] = (bf16)(x2 * cs + x1 * sn);
}

// Flash v2: BQ=64 (16 q-rows/wave), BK=64, d=256. Q frags in registers.
// q:(b,h,s,hd) k:(b,s,hd) v:(b,hd,s). LDS = 33.8+36.9+9.2 = 79.9KB -> 2/CU.
__global__ __launch_bounds__(256, 2)
void flash_bf16(const bf16* __restrict__ qg, const bf16* __restrict__ kg,
                const bf16* __restrict__ vg, const float* __restrict__ msk,
                bf16* __restrict__ ao) {
  __shared__ bf16 Ks[64 * KP];
  __shared__ bf16 Vs[256 * VP2];
  __shared__ bf16 Ps[64 * VP2];

  const int tid = threadIdx.x;
  const int lane = tid & 63;
  const int w = tid >> 6;
  const int c16 = lane & 15;
  const int quad = lane >> 4;

  const int qbi = blockIdx.x & 31;
  const int h = (blockIdx.x >> 5) & 7;
  const int b = blockIdx.x >> 8;
  const int q0 = qbi * 64;

  const bf16* qbase = qg + ((((size_t)b * H_NUM + h) * S_LEN + q0) << 8);
  const bf16* kbase = kg + ((size_t)b << 19);
  const bf16* vbase = vg + ((size_t)b << 19);
  const float* mbase = msk + (size_t)b * S_LEN * S_LEN +
                       (size_t)(q0 + w * 16 + quad * 4) * S_LEN;

  // Q A-fragments: one-time global->reg (16 rows/wave, contraction d=256)
  bf16x8 qf[8];
#pragma unroll
  for (int kd = 0; kd < 8; ++kd)
    qf[kd] = *(const bf16x8*)&qbase[((w * 16 + c16) << 8) + kd * 32 + quad * 8];

  f32x4 oacc[16];
#pragma unroll
  for (int t = 0; t < 16; ++t)
#pragma unroll
    for (int r = 0; r < 4; ++r) oacc[t][r] = 0.f;
  float mrow[4] = {-1e30f, -1e30f, -1e30f, -1e30f};
  float lrow[4] = {0.f, 0.f, 0.f, 0.f};

  for (int k0 = 0; k0 < S_LEN; k0 += 64) {
    // hoisted mask loads: independent of LDS, overlap staging latency
    float ml[4][4];
#pragma unroll
    for (int ct = 0; ct < 4; ++ct)
#pragma unroll
      for (int r = 0; r < 4; ++r)
        ml[ct][r] = mbase[(size_t)r * S_LEN + k0 + ct * 16 + c16];

    __syncthreads();  // prior iter's QK/PV done with Ks/Vs
    // stage K (64 x 256) and V^T (256 x 64)
#pragma unroll
    for (int i = 0; i < 8; ++i) {
      const int c = tid + i * 256;
      const int krow = c >> 5, kc = c & 31;
      *(bf16x8*)&Ks[krow * KP + kc * 8] =
          *(const bf16x8*)&kbase[((size_t)(k0 + krow) << 8) + kc * 8];
      const int vrow = c >> 3, vc = c & 7;
      *(bf16x8*)&Vs[vrow * VP2 + vc * 8] =
          *(const bf16x8*)&vbase[((size_t)vrow << 11) + k0 + vc * 8];
    }
    __syncthreads();

    // QK^T: 16 q-rows x 64 keys, d=256 -> 32 MFMAs
    f32x4 sc[4];
#pragma unroll
    for (int ct = 0; ct < 4; ++ct)
#pragma unroll
      for (int r = 0; r < 4; ++r) sc[ct][r] = 0.f;
#pragma unroll
    for (int kd = 0; kd < 8; ++kd) {
#pragma unroll
      for (int ct = 0; ct < 4; ++ct) {
        const bf16x8 bK = *(const bf16x8*)&Ks[(ct * 16 + c16) * KP + kd * 32 + quad * 8];
        sc[ct] = __builtin_amdgcn_mfma_f32_16x16x32_bf16(qf[kd], bK, sc[ct], 0, 0, 0);
      }
    }

    float sv[4][4];
#pragma unroll
    for (int ct = 0; ct < 4; ++ct)
#pragma unroll
      for (int r = 0; r < 4; ++r)
        sv[ct][r] = sc[ct][r] * 0.0625f + ml[ct][r];

    // online softmax (row = quad*4+r spread across 16 c16 lanes)
    float mloc[4], al[4], pv[4][4], rs[4];
#pragma unroll
    for (int r = 0; r < 4; ++r)
      mloc[r] = fmaxf(fmaxf(sv[0][r], sv[1][r]), fmaxf(sv[2][r], sv[3][r]));
#pragma unroll
    for (int d = 1; d < 16; d <<= 1)
#pragma unroll
      for (int r = 0; r < 4; ++r) mloc[r] = fmaxf(mloc[r], __shfl_xor(mloc[r], d, 64));
#pragma unroll
    for (int r = 0; r < 4; ++r) {
      const float mn = fmaxf(mrow[r], mloc[r]);
      al[r] = __expf(mrow[r] - mn);
#pragma unroll
      for (int ct = 0; ct < 4; ++ct) pv[ct][r] = __expf(sv[ct][r] - mn);
      rs[r] = (pv[0][r] + pv[1][r]) + (pv[2][r] + pv[3][r]);
      mrow[r] = mn;
    }
#pragma unroll
    for (int d = 1; d < 16; d <<= 1)
#pragma unroll
      for (int r = 0; r < 4; ++r) rs[r] += __shfl_xor(rs[r], d, 64);
#pragma unroll
    for (int r = 0; r < 4; ++r) lrow[r] = lrow[r] * al[r] + rs[r];

    // P (C-layout) -> LDS -> A-layout
#pragma unroll
    for (int ct = 0; ct < 4; ++ct)
#pragma unroll
      for (int r = 0; r < 4; ++r)
        Ps[(w * 16 + quad * 4 + r) * VP2 + ct * 16 + c16] = (bf16)pv[ct][r];
    __syncthreads();  // R2 lesson: barrier-separate P store/load

    // conditional O rescale (al==1 exactly when row max unchanged)
    const bool need = (al[0] < 1.f) | (al[1] < 1.f) | (al[2] < 1.f) | (al[3] < 1.f);
    if (__ballot(need) != 0ull) {
#pragma unroll
      for (int t = 0; t < 16; ++t)
#pragma unroll
        for (int r = 0; r < 4; ++r) oacc[t][r] *= al[r];
    }

    const bf16x8 pa0 = *(const bf16x8*)&Ps[(w * 16 + c16) * VP2 + quad * 8];
    const bf16x8 pa1 = *(const bf16x8*)&Ps[(w * 16 + c16) * VP2 + 32 + quad * 8];
#pragma unroll
    for (int t = 0; t < 16; ++t) {
      const bf16x8 v0 = *(const bf16x8*)&Vs[(t * 16 + c16) * VP2 + quad * 8];
      const bf16x8 v1 = *(const bf16x8*)&Vs[(t * 16 + c16) * VP2 + 32 + quad * 8];
      oacc[t] = __builtin_amdgcn_mfma_f32_16x16x32_bf16(pa0, v0, oacc[t], 0, 0, 0);
      oacc[t] = __builtin_amdgcn_mfma_f32_16x16x32_bf16(pa1, v1, oacc[t], 0, 0, 0);
    }
  }

  float li[4];
#pragma unroll
  for (int r = 0; r < 4; ++r) li[r] = 1.f / lrow[r];
  bf16* obase = ao + (size_t)(b * S_LEN + q0 + w * 16 + quad * 4) * D_MODEL + (h << 8);
#pragma unroll
  for (int t = 0; t < 16; ++t)
#pragma unroll
    for (int r = 0; r < 4; ++r)
      obase[(size_t)r * D_MODEL + t * 16 + c16] = (bf16)(oacc[t][r] * li[r]);
}

extern "C" void kernel_launch(void* const* d_in, const int* in_sizes, int n_in,
                              void* d_out, int out_size, void* d_ws, size_t ws_size,
                              hipStream_t stream) {
  const float* hs   = (const float*)d_in[0];
  const float* mask = (const float*)d_in[1];
  const int*   pos  = (const int*)d_in[2];
  const float* Wq   = (const float*)d_in[3];
  const float* Wk   = (const float*)d_in[4];
  const float* Wv   = (const float*)d_in[5];
  const float* Wo   = (const float*)d_in[6];
  float* out = (float*)d_out;

  const int B = in_sizes[2] / S_LEN;
  const int M = B * S_LEN;

  // ws: [hsb|aob 16.8M][Wqkvt 10.5M][Wot 8.4M][kb 2.1M][vb 2.1M] = 39.9MB
  char* wsc = (char*)d_ws;
  bf16* hsb = (bf16*)wsc;
  bf16* aob = hsb;  // flash output aliases hsb (dead after QKV gemm)
  size_t off = (size_t)M * D_MODEL * 2;
  bf16* Wqkvt = (bf16*)(wsc + off); off += (size_t)2560 * D_MODEL * 2;
  bf16* Wot   = (bf16*)(wsc + off); off += (size_t)D_MODEL * D_MODEL * 2;
  bf16* kb    = (bf16*)(wsc + off);
  bf16* vb    = kb + (size_t)M * HDIM;

  bf16* qb = (bf16*)d_out;  // overwritten by O-proj

  const dim3 blk(256);
  const dim3 tb(32, 8);
  cvt_bf16<<<(M * D_MODEL) / 1024, blk, 0, stream>>>(hs, hsb);
  tpose_cvt<<<dim3(64, 64), tb, 0, stream>>>(Wq, Wqkvt, D_MODEL, 0);
  tpose_cvt<<<dim3(8, 64), tb, 0, stream>>>(Wk, Wqkvt, HDIM, 2048);
  tpose_cvt<<<dim3(8, 64), tb, 0, stream>>>(Wv, Wqkvt, HDIM, 2304);
  tpose_cvt<<<dim3(64, 64), tb, 0, stream>>>(Wo, Wot, D_MODEL, 0);

  // fused Q+K+V projection: N = 2560
  gemm_bf16<<<dim3(20, M / 128), blk, 0, stream>>>(hsb, Wqkvt, qb, kb, vb, nullptr, M, 2560, 1);

  rope_q_bf16<<<(B * H_NUM * S_LEN * 128) / 256, blk, 0, stream>>>(qb, pos);
  rope_k_bf16<<<(B * S_LEN * 128) / 256, blk, 0, stream>>>(kb, pos);

  flash_bf16<<<B * H_NUM * (S_LEN / 64), blk, 0, stream>>>(qb, kb, vb, mask, aob);

  // O projection, fp32 out
  gemm_bf16<<<dim3(16, M / 128), blk, 0, stream>>>(aob, Wot, nullptr, nullptr, nullptr, out, M, D_MODEL, 3);
}